// Round 3
// baseline (3755.690 us; speedup 1.0000x reference)
//
#include <hip/hip_runtime.h>
#include <hip/hip_bf16.h>
#include <hip/hip_cooperative_groups.h>

namespace cg = cooperative_groups;

#define C       228
#define TT      1024
#define NPOS    2048      // B*T
#define LANESN  4
#define HD      57
#define VOC     50257
#define KPAD    256
#define HID     912
#define NLAYER  4
#define SCANBLK 512       // blocks in fused scan (2/CU co-resident, validated by coop launch)

typedef __bf16 bf16x8 __attribute__((ext_vector_type(8)));
typedef float  f32x4  __attribute__((ext_vector_type(4)));

__device__ __forceinline__ float rdl(float v, int lane) {
    return __int_as_float(__builtin_amdgcn_readlane(__float_as_int(v), lane));
}

// ---------------- weight transpose (generic) ----------------
__global__ void transpose_k(const float* __restrict__ src, float* __restrict__ dst,
                            int R, int Cc, int dstStride, int dstColOff,
                            int srcLayerStride, int dstLayerStride) {
    int layer = blockIdx.y;
    src += (size_t)layer * srcLayerStride;
    dst += (size_t)layer * dstLayerStride;
    int i = blockIdx.x * 256 + threadIdx.x;
    if (i < R * Cc) {
        int r = i / Cc, c = i - r * Cc;
        dst[(size_t)c * dstStride + dstColOff + r] = src[i];
    }
}

// ---------------- embedding ----------------
__global__ void embed_k(const int* __restrict__ idx, const float* __restrict__ wte,
                        float* __restrict__ x) {
    int i = blockIdx.x * 256 + threadIdx.x;   // NPOS*C total
    int n = i / C, c = i - n * C;
    x[i] = wte[(size_t)idx[n] * C + c];
}

// ---------------- LN + dual matmul (layer 0 entry) ----------------
__global__ __launch_bounds__(256) void lnuv_k(const float* __restrict__ x, const float* __restrict__ g,
                                              const float* __restrict__ wuvT,
                                              float* __restrict__ qout, float* __restrict__ vout) {
    __shared__ __align__(16) float hsh[4][256];
    int tid = threadIdx.x, nb = blockIdx.x * 4;
    int wv = tid >> 6, ln = tid & 63;
    const float* xr = x + (size_t)(nb + wv) * C;
    float vals[4]; float s = 0.f, ss = 0.f;
#pragma unroll
    for (int j = 0; j < 4; ++j) {
        int c = ln + 64 * j;
        float vv = (c < C) ? xr[c] : 0.f;
        vals[j] = vv; s += vv; ss += vv * vv;
    }
#pragma unroll
    for (int o = 32; o > 0; o >>= 1) { s += __shfl_xor(s, o, 64); ss += __shfl_xor(ss, o, 64); }
    float mean = s * (1.f / C);
    float rstd = rsqrtf(ss * (1.f / C) - mean * mean + 1e-5f);
#pragma unroll
    for (int j = 0; j < 4; ++j) {
        int c = ln + 64 * j;
        hsh[wv][c] = (c < C) ? (vals[j] - mean) * rstd * g[c] : 0.f;
    }
    __syncthreads();
    f32x4 hv[4];
#pragma unroll
    for (int p = 0; p < 4; ++p) hv[p] = *(const f32x4*)&hsh[p][4 * ln];
    int col0 = tid, col1 = tid + 256;
    int c1v = (col1 < 2 * C);
    float acc0[4] = {0,0,0,0}, acc1[4] = {0,0,0,0};
    const float* w0p = wuvT + col0;
    const float* w1p = wuvT + (c1v ? col1 : 0);
    for (int c4 = 0; c4 < 57; ++c4) {
        float wa0 = w0p[(size_t)(c4*4+0)*(2*C)], wa1 = w0p[(size_t)(c4*4+1)*(2*C)];
        float wa2 = w0p[(size_t)(c4*4+2)*(2*C)], wa3 = w0p[(size_t)(c4*4+3)*(2*C)];
        float wb0 = w1p[(size_t)(c4*4+0)*(2*C)], wb1 = w1p[(size_t)(c4*4+1)*(2*C)];
        float wb2 = w1p[(size_t)(c4*4+2)*(2*C)], wb3 = w1p[(size_t)(c4*4+3)*(2*C)];
#pragma unroll
        for (int p = 0; p < 4; ++p) {
            float h0 = rdl(hv[p].x, c4), h1 = rdl(hv[p].y, c4);
            float h2 = rdl(hv[p].z, c4), h3 = rdl(hv[p].w, c4);
            acc0[p] = fmaf(h0, wa0, acc0[p]); acc0[p] = fmaf(h1, wa1, acc0[p]);
            acc0[p] = fmaf(h2, wa2, acc0[p]); acc0[p] = fmaf(h3, wa3, acc0[p]);
            acc1[p] = fmaf(h0, wb0, acc1[p]); acc1[p] = fmaf(h1, wb1, acc1[p]);
            acc1[p] = fmaf(h2, wb2, acc1[p]); acc1[p] = fmaf(h3, wb3, acc1[p]);
        }
    }
#pragma unroll
    for (int p = 0; p < 4; ++p) {
        if (col0 < C) qout[(size_t)(nb+p)*C + col0] = acc0[p];
        else          vout[(size_t)(nb+p)*C + col0 - C] = acc0[p];
        if (c1v)      vout[(size_t)(nb+p)*C + col1 - C] = acc1[p];
    }
}

// ---------------- one scan step body (shared by fused & fallback) ----------------
__device__ __forceinline__ void scan_step_body(const float* __restrict__ src, float* __restrict__ dst,
                                               const float* __restrict__ wscan,
                                               const float* __restrict__ ident, int off,
                                               int nb, int tid, int wv, int ln,
                                               float lsh[4][232], float rsh[4][232],
                                               float ush[4][256], float vmsh[4][232],
                                               float zsh[4][232]) {
    // Phase A: load left/right, u = l + r
    for (int i = tid; i < 4 * C; i += 256) {
        int p = i / C, c = i - p * C;
        int n = nb + p, t = n & (TT - 1);
        float r = src[(size_t)n * C + c];
        float l = (t >= off) ? src[(size_t)(n - off) * C + c] : ident[c];
        lsh[p][c] = l; rsh[p][c] = r; ush[p][c] = l + r;
    }
    if (tid < 128) { int p = tid >> 5, c = 228 + (tid & 31); if (c < 256) ush[p][c] = 0.f; }
    __syncthreads();
    // Phase B: vmix = u @ wscan (col = tid, 4 positions)
    {
        int col = tid, colc = (col < C) ? col : 0;
        f32x4 hv0 = *(const f32x4*)&ush[0][4 * ln];
        f32x4 hv1 = *(const f32x4*)&ush[1][4 * ln];
        f32x4 hv2 = *(const f32x4*)&ush[2][4 * ln];
        f32x4 hv3 = *(const f32x4*)&ush[3][4 * ln];
        float a0 = 0.f, a1 = 0.f, a2 = 0.f, a3 = 0.f;
        const float* wcol = wscan + colc;
        for (int c4 = 0; c4 < 57; ++c4) {
            float w0 = wcol[(size_t)(c4*4+0)*C];
            float w1 = wcol[(size_t)(c4*4+1)*C];
            float w2 = wcol[(size_t)(c4*4+2)*C];
            float w3 = wcol[(size_t)(c4*4+3)*C];
            a0 = fmaf(rdl(hv0.x, c4), w0, a0); a0 = fmaf(rdl(hv0.y, c4), w1, a0);
            a0 = fmaf(rdl(hv0.z, c4), w2, a0); a0 = fmaf(rdl(hv0.w, c4), w3, a0);
            a1 = fmaf(rdl(hv1.x, c4), w0, a1); a1 = fmaf(rdl(hv1.y, c4), w1, a1);
            a1 = fmaf(rdl(hv1.z, c4), w2, a1); a1 = fmaf(rdl(hv1.w, c4), w3, a1);
            a2 = fmaf(rdl(hv2.x, c4), w0, a2); a2 = fmaf(rdl(hv2.y, c4), w1, a2);
            a2 = fmaf(rdl(hv2.z, c4), w2, a2); a2 = fmaf(rdl(hv2.w, c4), w3, a2);
            a3 = fmaf(rdl(hv3.x, c4), w0, a3); a3 = fmaf(rdl(hv3.y, c4), w1, a3);
            a3 = fmaf(rdl(hv3.z, c4), w2, a3); a3 = fmaf(rdl(hv3.w, c4), w3, a3);
        }
        if (col < C) { vmsh[0][col] = a0; vmsh[1][col] = a1; vmsh[2][col] = a2; vmsh[3][col] = a3; }
    }
    __syncthreads();
    // Phase C: wave-local attention, position = wv
    float att = 0.f;
    {
        int l = (ln >> 2) & 3, m = ln & 3;
        float sc = 0.f;
        if (ln < 16) {
            const float* qv = &lsh[wv][l * HD];
            const float* kv = &rsh[wv][m * HD];
            for (int d = 0; d < HD; ++d) sc = fmaf(qv[d], kv[d], sc);
            sc *= 0.13245323570650439f;  // 1/sqrt(57)
        }
        float mx = fmaxf(sc, __shfl_xor(sc, 1, 4));
        mx = fmaxf(mx, __shfl_xor(mx, 2, 4));
        float e = expf(sc - mx);
        float se = e + __shfl_xor(e, 1, 4);
        se += __shfl_xor(se, 2, 4);
        att = e / se;
    }
    float zreg[4]; int lidx[4];
#pragma unroll
    for (int j = 0; j < 4; ++j) {
        int c = ln + 64 * j;
        zreg[j] = 0.f; lidx[j] = 0;
        if (c < C) {
            int l = (c >= 171) + (c >= 114) + (c >= 57);
            int d = c - 57 * l;
            float b0 = __shfl(att, 4 * l + 0, 64);
            float b1 = __shfl(att, 4 * l + 1, 64);
            float b2 = __shfl(att, 4 * l + 2, 64);
            float b3 = __shfl(att, 4 * l + 3, 64);
            float z = b0 * vmsh[wv][d] + b1 * vmsh[wv][HD + d]
                    + b2 * vmsh[wv][2 * HD + d] + b3 * vmsh[wv][3 * HD + d];
            zsh[wv][c] = z; zreg[j] = z; lidx[j] = l;
        }
    }
    float rs = 0.f;
    if (ln < 4) {
        float zz = 0.f;
        const float* zr = &zsh[wv][ln * HD];
        for (int d = 0; d < HD; ++d) zz = fmaf(zr[d], zr[d], zz);
        rs = rsqrtf(zz * (1.f / HD) + 1e-6f) / (float)(1 + ln);
    }
#pragma unroll
    for (int j = 0; j < 4; ++j) {
        int c = ln + 64 * j;
        if (c < C) {
            float rsl = __shfl(rs, lidx[j], 64);
            dst[(size_t)(nb + wv) * C + c] = lsh[wv][c] + zreg[j] * rsl;
        }
    }
}

// ---------------- fused 10-step scan (cooperative, one launch per layer) ----------------
__global__ __launch_bounds__(256, 2) void scanfused_k(float* buf0, float* buf1,
                                                      const float* __restrict__ wscan,
                                                      const float* __restrict__ ident) {
    __shared__ __align__(16) float lsh[4][232];
    __shared__ __align__(16) float rsh[4][232];
    __shared__ __align__(16) float ush[4][256];
    __shared__ __align__(16) float vmsh[4][232];
    __shared__ __align__(16) float zsh[4][232];
    cg::grid_group grid = cg::this_grid();
    int tid = threadIdx.x, nb = blockIdx.x * 4;
    int wv = tid >> 6, ln = tid & 63;
    const float* src = buf0;
    float* dst = buf1;
    for (int off = 1; off < TT; off <<= 1) {
        scan_step_body(src, dst, wscan, ident, off, nb, tid, wv, ln, lsh, rsh, ush, vmsh, zsh);
        { const float* t = src; src = dst; dst = (float*)t; }
        if (off < 512) { grid.sync(); __syncthreads(); }
    }
    // 10 steps (even) -> final result in buf0
}

// ---------------- fallback: one step per launch ----------------
__global__ __launch_bounds__(256, 2) void scanstep_k(const float* __restrict__ src, float* __restrict__ dst,
                                                     const float* __restrict__ wscan,
                                                     const float* __restrict__ ident, int off) {
    __shared__ __align__(16) float lsh[4][232];
    __shared__ __align__(16) float rsh[4][232];
    __shared__ __align__(16) float ush[4][256];
    __shared__ __align__(16) float vmsh[4][232];
    __shared__ __align__(16) float zsh[4][232];
    int tid = threadIdx.x, nb = blockIdx.x * 4;
    int wv = tid >> 6, ln = tid & 63;
    scan_step_body(src, dst, wscan, ident, off, nb, tid, wv, ln, lsh, rsh, ush, vmsh, zsh);
}

// ---------------- fused MLP: x += cproj; LN2; fc+gelu; proj(+res); [LN1'; uv'] ----------------
__global__ __launch_bounds__(256) void mlp_k(const float* __restrict__ q, const float* __restrict__ v,
                                             const float* __restrict__ wcT, const float* __restrict__ g2,
                                             const float* __restrict__ wfcT, const float* __restrict__ wpT,
                                             float* __restrict__ x,
                                             const float* __restrict__ g1n, const float* __restrict__ wuvTn,
                                             float* __restrict__ qout, float* __restrict__ vout) {
    __shared__ __align__(16) float psh[4][256];   // q*v, later x_final
    __shared__ __align__(16) float xm[4][232];    // x + cproj
    __shared__ __align__(16) float hsh[4][256];   // LN outputs
    __shared__ __align__(16) float hid[4][944];   // gelu(fc)
    int tid = threadIdx.x, nb = blockIdx.x * 4;
    int wv = tid >> 6, ln = tid & 63;
    for (int i = tid; i < 4 * 256; i += 256) {
        int p = i >> 8, c = i & 255;
        psh[p][c] = (c < C) ? q[(size_t)(nb + p) * C + c] * v[(size_t)(nb + p) * C + c] : 0.f;
    }
    if (tid < 128) { int p = tid >> 5; hid[p][912 + (tid & 31)] = 0.f; }
    __syncthreads();
    // GEMV1: cproj, xm = x + p @ wcT
    {
        int col = tid, colc = (col < C) ? col : 0;
        f32x4 hv0 = *(const f32x4*)&psh[0][4 * ln];
        f32x4 hv1 = *(const f32x4*)&psh[1][4 * ln];
        f32x4 hv2 = *(const f32x4*)&psh[2][4 * ln];
        f32x4 hv3 = *(const f32x4*)&psh[3][4 * ln];
        float a0 = 0.f, a1 = 0.f, a2 = 0.f, a3 = 0.f;
        const float* wcol = wcT + colc;
        for (int c4 = 0; c4 < 57; ++c4) {
            float w0 = wcol[(size_t)(c4*4+0)*C];
            float w1 = wcol[(size_t)(c4*4+1)*C];
            float w2 = wcol[(size_t)(c4*4+2)*C];
            float w3 = wcol[(size_t)(c4*4+3)*C];
            a0 = fmaf(rdl(hv0.x, c4), w0, a0); a0 = fmaf(rdl(hv0.y, c4), w1, a0);
            a0 = fmaf(rdl(hv0.z, c4), w2, a0); a0 = fmaf(rdl(hv0.w, c4), w3, a0);
            a1 = fmaf(rdl(hv1.x, c4), w0, a1); a1 = fmaf(rdl(hv1.y, c4), w1, a1);
            a1 = fmaf(rdl(hv1.z, c4), w2, a1); a1 = fmaf(rdl(hv1.w, c4), w3, a1);
            a2 = fmaf(rdl(hv2.x, c4), w0, a2); a2 = fmaf(rdl(hv2.y, c4), w1, a2);
            a2 = fmaf(rdl(hv2.z, c4), w2, a2); a2 = fmaf(rdl(hv2.w, c4), w3, a2);
            a3 = fmaf(rdl(hv3.x, c4), w0, a3); a3 = fmaf(rdl(hv3.y, c4), w1, a3);
            a3 = fmaf(rdl(hv3.z, c4), w2, a3); a3 = fmaf(rdl(hv3.w, c4), w3, a3);
        }
        if (col < C) {
            xm[0][col] = x[(size_t)(nb+0)*C + col] + a0;
            xm[1][col] = x[(size_t)(nb+1)*C + col] + a1;
            xm[2][col] = x[(size_t)(nb+2)*C + col] + a2;
            xm[3][col] = x[(size_t)(nb+3)*C + col] + a3;
        }
    }
    __syncthreads();
    // LN2 per wave
    {
        float vals[4]; float s = 0.f, ss = 0.f;
#pragma unroll
        for (int j = 0; j < 4; ++j) {
            int c = ln + 64 * j;
            float vv = (c < C) ? xm[wv][c] : 0.f;
            vals[j] = vv; s += vv; ss += vv * vv;
        }
#pragma unroll
        for (int o = 32; o > 0; o >>= 1) { s += __shfl_xor(s, o, 64); ss += __shfl_xor(ss, o, 64); }
        float mean = s * (1.f / C);
        float rstd = rsqrtf(ss * (1.f / C) - mean * mean + 1e-5f);
#pragma unroll
        for (int j = 0; j < 4; ++j) {
            int c = ln + 64 * j;
            hsh[wv][c] = (c < C) ? (vals[j] - mean) * rstd * g2[c] : 0.f;
        }
    }
    __syncthreads();
    // GEMV2: fc + gelu, 4 cols/thread
    {
        f32x4 hv[4];
#pragma unroll
        for (int p = 0; p < 4; ++p) hv[p] = *(const f32x4*)&hsh[p][4 * ln];
        int c0 = tid, c1 = tid + 256, c2 = tid + 512, c3 = tid + 768;
        int c3v = (c3 < HID);
        const float* wp0 = wfcT + c0;
        const float* wp1 = wfcT + c1;
        const float* wp2 = wfcT + c2;
        const float* wp3 = wfcT + (c3v ? c3 : 0);
        float acc[4][4] = {};
        for (int c4 = 0; c4 < 57; ++c4) {
            float wa0 = wp0[(size_t)(c4*4+0)*HID], wa1 = wp0[(size_t)(c4*4+1)*HID];
            float wa2 = wp0[(size_t)(c4*4+2)*HID], wa3 = wp0[(size_t)(c4*4+3)*HID];
            float wb0 = wp1[(size_t)(c4*4+0)*HID], wb1 = wp1[(size_t)(c4*4+1)*HID];
            float wb2 = wp1[(size_t)(c4*4+2)*HID], wb3 = wp1[(size_t)(c4*4+3)*HID];
            float wc0 = wp2[(size_t)(c4*4+0)*HID], wc1 = wp2[(size_t)(c4*4+1)*HID];
            float wc2 = wp2[(size_t)(c4*4+2)*HID], wc3 = wp2[(size_t)(c4*4+3)*HID];
            float wd0 = wp3[(size_t)(c4*4+0)*HID], wd1 = wp3[(size_t)(c4*4+1)*HID];
            float wd2 = wp3[(size_t)(c4*4+2)*HID], wd3 = wp3[(size_t)(c4*4+3)*HID];
#pragma unroll
            for (int p = 0; p < 4; ++p) {
                float h0 = rdl(hv[p].x, c4), h1 = rdl(hv[p].y, c4);
                float h2 = rdl(hv[p].z, c4), h3 = rdl(hv[p].w, c4);
                acc[0][p] = fmaf(h0, wa0, acc[0][p]); acc[0][p] = fmaf(h1, wa1, acc[0][p]);
                acc[0][p] = fmaf(h2, wa2, acc[0][p]); acc[0][p] = fmaf(h3, wa3, acc[0][p]);
                acc[1][p] = fmaf(h0, wb0, acc[1][p]); acc[1][p] = fmaf(h1, wb1, acc[1][p]);
                acc[1][p] = fmaf(h2, wb2, acc[1][p]); acc[1][p] = fmaf(h3, wb3, acc[1][p]);
                acc[2][p] = fmaf(h0, wc0, acc[2][p]); acc[2][p] = fmaf(h1, wc1, acc[2][p]);
                acc[2][p] = fmaf(h2, wc2, acc[2][p]); acc[2][p] = fmaf(h3, wc3, acc[2][p]);
                acc[3][p] = fmaf(h0, wd0, acc[3][p]); acc[3][p] = fmaf(h1, wd1, acc[3][p]);
                acc[3][p] = fmaf(h2, wd2, acc[3][p]); acc[3][p] = fmaf(h3, wd3, acc[3][p]);
            }
        }
#pragma unroll
        for (int p = 0; p < 4; ++p) {
            float u0 = acc[0][p], u1 = acc[1][p], u2 = acc[2][p], u3 = acc[3][p];
            hid[p][c0] = 0.5f * u0 * (1.f + tanhf(0.7978845608028654f * (u0 + 0.044715f * u0 * u0 * u0)));
            hid[p][c1] = 0.5f * u1 * (1.f + tanhf(0.7978845608028654f * (u1 + 0.044715f * u1 * u1 * u1)));
            hid[p][c2] = 0.5f * u2 * (1.f + tanhf(0.7978845608028654f * (u2 + 0.044715f * u2 * u2 * u2)));
            if (c3v) hid[p][c3] = 0.5f * u3 * (1.f + tanhf(0.7978845608028654f * (u3 + 0.044715f * u3 * u3 * u3)));
        }
    }
    __syncthreads();
    // GEMV3: proj + residual; write x global + psh (x_final)
    {
        int col = tid, colc = (col < C) ? col : 0;
        float a[4] = {0,0,0,0};
        const float* wcol = wpT + colc;
        for (int ch = 0; ch < 4; ++ch) {
            f32x4 hv[4];
#pragma unroll
            for (int p = 0; p < 4; ++p) hv[p] = *(const f32x4*)&hid[p][228 * ch + 4 * ln];
            const float* wch = wcol + (size_t)(228 * ch) * C;
            for (int c4 = 0; c4 < 57; ++c4) {
                float w0 = wch[(size_t)(c4*4+0)*C];
                float w1 = wch[(size_t)(c4*4+1)*C];
                float w2 = wch[(size_t)(c4*4+2)*C];
                float w3 = wch[(size_t)(c4*4+3)*C];
#pragma unroll
                for (int p = 0; p < 4; ++p) {
                    a[p] = fmaf(rdl(hv[p].x, c4), w0, a[p]);
                    a[p] = fmaf(rdl(hv[p].y, c4), w1, a[p]);
                    a[p] = fmaf(rdl(hv[p].z, c4), w2, a[p]);
                    a[p] = fmaf(rdl(hv[p].w, c4), w3, a[p]);
                }
            }
        }
        if (col < C) {
#pragma unroll
            for (int p = 0; p < 4; ++p) {
                float xf = xm[p][col] + a[p];
                x[(size_t)(nb + p) * C + col] = xf;
                psh[p][col] = xf;
            }
        }
    }
    if (qout != nullptr) {
        __syncthreads();
        // LN1 (next layer) per wave from psh
        {
            float vals[4]; float s = 0.f, ss = 0.f;
#pragma unroll
            for (int j = 0; j < 4; ++j) {
                int c = ln + 64 * j;
                float vv = (c < C) ? psh[wv][c] : 0.f;
                vals[j] = vv; s += vv; ss += vv * vv;
            }
#pragma unroll
            for (int o = 32; o > 0; o >>= 1) { s += __shfl_xor(s, o, 64); ss += __shfl_xor(ss, o, 64); }
            float mean = s * (1.f / C);
            float rstd = rsqrtf(ss * (1.f / C) - mean * mean + 1e-5f);
#pragma unroll
            for (int j = 0; j < 4; ++j) {
                int c = ln + 64 * j;
                hsh[wv][c] = (c < C) ? (vals[j] - mean) * rstd * g1n[c] : 0.f;
            }
        }
        __syncthreads();
        // GEMV4: next-layer up/v
        f32x4 hv[4];
#pragma unroll
        for (int p = 0; p < 4; ++p) hv[p] = *(const f32x4*)&hsh[p][4 * ln];
        int col0 = tid, col1 = tid + 256;
        int c1v = (col1 < 2 * C);
        float acc0[4] = {0,0,0,0}, acc1[4] = {0,0,0,0};
        const float* w0p = wuvTn + col0;
        const float* w1p = wuvTn + (c1v ? col1 : 0);
        for (int c4 = 0; c4 < 57; ++c4) {
            float wa0 = w0p[(size_t)(c4*4+0)*(2*C)], wa1 = w0p[(size_t)(c4*4+1)*(2*C)];
            float wa2 = w0p[(size_t)(c4*4+2)*(2*C)], wa3 = w0p[(size_t)(c4*4+3)*(2*C)];
            float wb0 = w1p[(size_t)(c4*4+0)*(2*C)], wb1 = w1p[(size_t)(c4*4+1)*(2*C)];
            float wb2 = w1p[(size_t)(c4*4+2)*(2*C)], wb3 = w1p[(size_t)(c4*4+3)*(2*C)];
#pragma unroll
            for (int p = 0; p < 4; ++p) {
                float h0 = rdl(hv[p].x, c4), h1 = rdl(hv[p].y, c4);
                float h2 = rdl(hv[p].z, c4), h3 = rdl(hv[p].w, c4);
                acc0[p] = fmaf(h0, wa0, acc0[p]); acc0[p] = fmaf(h1, wa1, acc0[p]);
                acc0[p] = fmaf(h2, wa2, acc0[p]); acc0[p] = fmaf(h3, wa3, acc0[p]);
                acc1[p] = fmaf(h0, wb0, acc1[p]); acc1[p] = fmaf(h1, wb1, acc1[p]);
                acc1[p] = fmaf(h2, wb2, acc1[p]); acc1[p] = fmaf(h3, wb3, acc1[p]);
            }
        }
#pragma unroll
        for (int p = 0; p < 4; ++p) {
            if (col0 < C) qout[(size_t)(nb+p)*C + col0] = acc0[p];
            else          vout[(size_t)(nb+p)*C + col0 - C] = acc0[p];
            if (c1v)      vout[(size_t)(nb+p)*C + col1 - C] = acc1[p];
        }
    }
}

// ---------------- bf16 conversions (K padded to 256 with zeros) ----------------
__global__ void convx_k(const float* __restrict__ x, __hip_bfloat16* __restrict__ xbf) {
    int i = blockIdx.x * 256 + threadIdx.x;    // NPOS*KPAD total
    int n = i >> 8, c = i & 255;
    xbf[i] = __float2bfloat16((c < C) ? x[(size_t)n * C + c] : 0.f);
}
__global__ void convw_k(const float* __restrict__ wte, __hip_bfloat16* __restrict__ wbf) {
    size_t i = (size_t)blockIdx.x * 256 + threadIdx.x;   // VOC*KPAD total
    size_t n = i >> 8; int c = (int)(i & 255);
    wbf[i] = __float2bfloat16((c < C) ? wte[n * C + c] : 0.f);
}

// ---------------- lm_head: out[2048][VOC] = A @ B^T (bf16 MFMA) ----------------
__global__ __launch_bounds__(256) void lmhead_k(const __bf16* __restrict__ A,
                                                const __bf16* __restrict__ Bw,
                                                float* __restrict__ out) {
    int lane = threadIdx.x & 63;
    int wave = threadIdx.x >> 6;
    int wm = wave >> 1, wn = wave & 1;
    int m0 = blockIdx.x * 128 + wm * 64;
    int n0 = blockIdx.y * 128 + wn * 64;
    int r  = lane & 15, q = lane >> 4;
    f32x4 acc[4][4] = {};
    const __bf16* Ap = A + (size_t)(m0 + r) * KPAD + q * 8;
    int brow[4];
#pragma unroll
    for (int nt = 0; nt < 4; ++nt) { int rw = n0 + nt * 16 + r; brow[nt] = (rw < VOC) ? rw : 0; }
    for (int kc = 0; kc < 8; ++kc) {
        int ko = kc * 32;
        bf16x8 a[4], b[4];
#pragma unroll
        for (int mt = 0; mt < 4; ++mt)
            a[mt] = *(const bf16x8*)(Ap + (size_t)mt * 16 * KPAD + ko);
#pragma unroll
        for (int nt = 0; nt < 4; ++nt)
            b[nt] = *(const bf16x8*)(Bw + (size_t)brow[nt] * KPAD + q * 8 + ko);
#pragma unroll
        for (int mt = 0; mt < 4; ++mt)
#pragma unroll
            for (int nt = 0; nt < 4; ++nt)
                acc[mt][nt] = __builtin_amdgcn_mfma_f32_16x16x32_bf16(a[mt], b[nt], acc[mt][nt], 0, 0, 0);
    }
#pragma unroll
    for (int mt = 0; mt < 4; ++mt)
#pragma unroll
        for (int nt = 0; nt < 4; ++nt) {
            int col = n0 + nt * 16 + r;
            if (col < VOC) {
#pragma unroll
                for (int rr = 0; rr < 4; ++rr) {
                    int row = m0 + mt * 16 + q * 4 + rr;
                    out[(size_t)row * VOC + col] = acc[mt][nt][rr];
                }
            }
        }
}

extern "C" void kernel_launch(void* const* d_in, const int* in_sizes, int n_in,
                              void* d_out, int out_size, void* d_ws, size_t ws_size,
                              hipStream_t stream) {
    const int*   idx     = (const int*)d_in[0];
    const float* wte     = (const float*)d_in[1];
    const float* ln1_g   = (const float*)d_in[2];
    const float* ln2_g   = (const float*)d_in[3];
    const float* w_up    = (const float*)d_in[4];
    const float* w_v     = (const float*)d_in[5];
    const float* w_cproj = (const float*)d_in[6];
    const float* w_scan  = (const float*)d_in[7];
    const float* identp  = (const float*)d_in[8];
    const float* w_fc    = (const float*)d_in[9];
    const float* w_proj  = (const float*)d_in[10];
    float* out = (float*)d_out;

    float* ws   = (float*)d_ws;
    float* x    = ws;
    float* buf0 = x    + (size_t)NPOS * C;
    float* buf1 = buf0 + (size_t)NPOS * C;
    float* vbuf = buf1 + (size_t)NPOS * C;
    float* wuvT = vbuf + (size_t)NPOS * C;
    float* wcT  = wuvT + (size_t)NLAYER * C * 2 * C;
    float* wfcT = wcT  + (size_t)NLAYER * C * C;
    float* wpT  = wfcT + (size_t)NLAYER * C * HID;
    __hip_bfloat16* xbf   = (__hip_bfloat16*)(wpT + (size_t)NLAYER * HID * C);
    __hip_bfloat16* wtebf = xbf + (size_t)NPOS * KPAD;

    // cooperative-launch support check (host-side attribute query; capture-safe)
    int coop = 0;
    {
        int dev = 0;
        hipGetDevice(&dev);
        hipDeviceGetAttribute(&coop, hipDeviceAttributeCooperativeLaunch, dev);
    }

    dim3 tg1((C * C + 255) / 256, NLAYER);
    transpose_k<<<tg1, 256, 0, stream>>>(w_up,    wuvT, C, C, 2 * C, 0, C * C, C * 2 * C);
    transpose_k<<<tg1, 256, 0, stream>>>(w_v,     wuvT, C, C, 2 * C, C, C * C, C * 2 * C);
    transpose_k<<<tg1, 256, 0, stream>>>(w_cproj, wcT,  C, C, C,     0, C * C, C * C);
    dim3 tg2((HID * C + 255) / 256, NLAYER);
    transpose_k<<<tg2, 256, 0, stream>>>(w_fc,   wfcT, HID, C, HID, 0, HID * C, C * HID);
    transpose_k<<<tg2, 256, 0, stream>>>(w_proj, wpT,  C, HID, C,   0, C * HID, HID * C);

    embed_k<<<NPOS * C / 256, 256, 0, stream>>>(idx, wte, x);

    lnuv_k<<<NPOS / 4, 256, 0, stream>>>(x, ln1_g, wuvT, buf0, vbuf);
    for (int L = 0; L < NLAYER; ++L) {
        const float* wscan_l = w_scan + (size_t)L * C * C;
        const float* ident_l = identp + (size_t)L * C;
        bool fused_ok = false;
        if (coop) {
            float* a0 = buf0; float* a1 = buf1;
            void* args[] = { &a0, &a1, (void*)&wscan_l, (void*)&ident_l };
            hipError_t e = hipLaunchCooperativeKernel((const void*)scanfused_k,
                                                      dim3(SCANBLK), dim3(256), args, 0, stream);
            fused_ok = (e == hipSuccess);
        }
        if (!fused_ok) {
            float* cur = buf0; float* oth = buf1;
            for (int off = 1; off < TT; off <<= 1) {
                scanstep_k<<<NPOS / 4, 256, 0, stream>>>(cur, oth, wscan_l, ident_l, off);
                float* t = cur; cur = oth; oth = t;
            }
            // 10 steps (even) -> result back in buf0
        }
        bool last = (L == NLAYER - 1);
        mlp_k<<<NPOS / 4, 256, 0, stream>>>(buf0, vbuf,
                                            wcT  + (size_t)L * C * C,
                                            ln2_g + L * C,
                                            wfcT + (size_t)L * C * HID,
                                            wpT  + (size_t)L * HID * C,
                                            x,
                                            last ? nullptr : (ln1_g + (size_t)(L + 1) * C),
                                            last ? nullptr : (wuvT + (size_t)(L + 1) * C * 2 * C),
                                            last ? nullptr : buf0,
                                            last ? nullptr : vbuf);
    }

    convx_k<<<NPOS * KPAD / 256, 256, 0, stream>>>(x, xbf);
    convw_k<<<VOC, 256, 0, stream>>>(wte, wtebf);
    lmhead_k<<<dim3(16, 393), 256, 0, stream>>>((const __bf16*)xbf, (const __bf16*)wtebf, out);
}

// Round 4
// 1688.916 us; speedup vs baseline: 2.2237x; 2.2237x over previous
//
#include <hip/hip_runtime.h>
#include <hip/hip_bf16.h>

#define C       228
#define TT      1024
#define NPOS    2048      // B*T
#define LANESN  4
#define HD      57
#define VOC     50257
#define KPAD    256
#define HID     912
#define NLAYER  4

typedef __bf16 bf16x8 __attribute__((ext_vector_type(8)));
typedef float  f32x4  __attribute__((ext_vector_type(4)));

__device__ __forceinline__ float rdl(float v, int lane) {
    return __int_as_float(__builtin_amdgcn_readlane(__float_as_int(v), lane));
}

// ---------------- weight transpose (generic) ----------------
__global__ void transpose_k(const float* __restrict__ src, float* __restrict__ dst,
                            int R, int Cc, int dstStride, int dstColOff,
                            int srcLayerStride, int dstLayerStride) {
    int layer = blockIdx.y;
    src += (size_t)layer * srcLayerStride;
    dst += (size_t)layer * dstLayerStride;
    int i = blockIdx.x * 256 + threadIdx.x;
    if (i < R * Cc) {
        int r = i / Cc, c = i - r * Cc;
        dst[(size_t)c * dstStride + dstColOff + r] = src[i];
    }
}

// ---------------- embedding ----------------
__global__ void embed_k(const int* __restrict__ idx, const float* __restrict__ wte,
                        float* __restrict__ x) {
    int i = blockIdx.x * 256 + threadIdx.x;   // NPOS*C total
    int n = i / C, c = i - n * C;
    x[i] = wte[(size_t)idx[n] * C + c];
}

// ---------------- LN + dual matmul (layer 0 entry) ----------------
__global__ __launch_bounds__(256) void lnuv_k(const float* __restrict__ x, const float* __restrict__ g,
                                              const float* __restrict__ wuvT,
                                              float* __restrict__ qout, float* __restrict__ vout) {
    __shared__ __align__(16) float hsh[4][256];
    int tid = threadIdx.x, nb = blockIdx.x * 4;
    int wv = tid >> 6, ln = tid & 63;
    const float* xr = x + (size_t)(nb + wv) * C;
    float vals[4]; float s = 0.f, ss = 0.f;
#pragma unroll
    for (int j = 0; j < 4; ++j) {
        int c = ln + 64 * j;
        float vv = (c < C) ? xr[c] : 0.f;
        vals[j] = vv; s += vv; ss += vv * vv;
    }
#pragma unroll
    for (int o = 32; o > 0; o >>= 1) { s += __shfl_xor(s, o, 64); ss += __shfl_xor(ss, o, 64); }
    float mean = s * (1.f / C);
    float rstd = rsqrtf(ss * (1.f / C) - mean * mean + 1e-5f);
#pragma unroll
    for (int j = 0; j < 4; ++j) {
        int c = ln + 64 * j;
        hsh[wv][c] = (c < C) ? (vals[j] - mean) * rstd * g[c] : 0.f;
    }
    __syncthreads();
    f32x4 hv[4];
#pragma unroll
    for (int p = 0; p < 4; ++p) hv[p] = *(const f32x4*)&hsh[p][4 * ln];
    int col0 = tid, col1 = tid + 256;
    int c1v = (col1 < 2 * C);
    float acc0[4] = {0,0,0,0}, acc1[4] = {0,0,0,0};
    const float* w0p = wuvT + col0;
    const float* w1p = wuvT + (c1v ? col1 : 0);
    for (int c4 = 0; c4 < 57; ++c4) {
        float wa0 = w0p[(size_t)(c4*4+0)*(2*C)], wa1 = w0p[(size_t)(c4*4+1)*(2*C)];
        float wa2 = w0p[(size_t)(c4*4+2)*(2*C)], wa3 = w0p[(size_t)(c4*4+3)*(2*C)];
        float wb0 = w1p[(size_t)(c4*4+0)*(2*C)], wb1 = w1p[(size_t)(c4*4+1)*(2*C)];
        float wb2 = w1p[(size_t)(c4*4+2)*(2*C)], wb3 = w1p[(size_t)(c4*4+3)*(2*C)];
#pragma unroll
        for (int p = 0; p < 4; ++p) {
            float h0 = rdl(hv[p].x, c4), h1 = rdl(hv[p].y, c4);
            float h2 = rdl(hv[p].z, c4), h3 = rdl(hv[p].w, c4);
            acc0[p] = fmaf(h0, wa0, acc0[p]); acc0[p] = fmaf(h1, wa1, acc0[p]);
            acc0[p] = fmaf(h2, wa2, acc0[p]); acc0[p] = fmaf(h3, wa3, acc0[p]);
            acc1[p] = fmaf(h0, wb0, acc1[p]); acc1[p] = fmaf(h1, wb1, acc1[p]);
            acc1[p] = fmaf(h2, wb2, acc1[p]); acc1[p] = fmaf(h3, wb3, acc1[p]);
        }
    }
#pragma unroll
    for (int p = 0; p < 4; ++p) {
        if (col0 < C) qout[(size_t)(nb+p)*C + col0] = acc0[p];
        else          vout[(size_t)(nb+p)*C + col0 - C] = acc0[p];
        if (c1v)      vout[(size_t)(nb+p)*C + col1 - C] = acc1[p];
    }
}

// ---------------- one scan step per launch ----------------
__global__ __launch_bounds__(256, 2) void scanstep_k(const float* __restrict__ src, float* __restrict__ dst,
                                                     const float* __restrict__ wscan,
                                                     const float* __restrict__ ident, int off) {
    __shared__ __align__(16) float lsh[4][232];
    __shared__ __align__(16) float rsh[4][232];
    __shared__ __align__(16) float ush[4][256];
    __shared__ __align__(16) float vmsh[4][232];
    __shared__ __align__(16) float zsh[4][232];
    int tid = threadIdx.x, nb = blockIdx.x * 4;
    int wv = tid >> 6, ln = tid & 63;
    // Phase A: load left/right, u = l + r
    for (int i = tid; i < 4 * C; i += 256) {
        int p = i / C, c = i - p * C;
        int n = nb + p, t = n & (TT - 1);
        float r = src[(size_t)n * C + c];
        float l = (t >= off) ? src[(size_t)(n - off) * C + c] : ident[c];
        lsh[p][c] = l; rsh[p][c] = r; ush[p][c] = l + r;
    }
    if (tid < 128) { int p = tid >> 5, c = 228 + (tid & 31); if (c < 256) ush[p][c] = 0.f; }
    __syncthreads();
    // Phase B: vmix = u @ wscan (col = tid, 4 positions), 1-iter register prefetch
    {
        int col = tid, colc = (col < C) ? col : 0;
        f32x4 hv0 = *(const f32x4*)&ush[0][4 * ln];
        f32x4 hv1 = *(const f32x4*)&ush[1][4 * ln];
        f32x4 hv2 = *(const f32x4*)&ush[2][4 * ln];
        f32x4 hv3 = *(const f32x4*)&ush[3][4 * ln];
        float a0 = 0.f, a1 = 0.f, a2 = 0.f, a3 = 0.f;
        const float* wcol = wscan + colc;
        float w0 = wcol[0 * C], w1 = wcol[1 * C], w2 = wcol[2 * C], w3 = wcol[3 * C];
        const float* wnext = wcol + (size_t)4 * C;
        for (int c4 = 0; c4 < 57; ++c4) {
            float p0 = 0.f, p1 = 0.f, p2 = 0.f, p3 = 0.f;
            if (c4 < 56) {
                p0 = wnext[0 * C]; p1 = wnext[1 * C];
                p2 = wnext[2 * C]; p3 = wnext[3 * C];
                wnext += (size_t)4 * C;
            }
            a0 = fmaf(rdl(hv0.x, c4), w0, a0); a0 = fmaf(rdl(hv0.y, c4), w1, a0);
            a0 = fmaf(rdl(hv0.z, c4), w2, a0); a0 = fmaf(rdl(hv0.w, c4), w3, a0);
            a1 = fmaf(rdl(hv1.x, c4), w0, a1); a1 = fmaf(rdl(hv1.y, c4), w1, a1);
            a1 = fmaf(rdl(hv1.z, c4), w2, a1); a1 = fmaf(rdl(hv1.w, c4), w3, a1);
            a2 = fmaf(rdl(hv2.x, c4), w0, a2); a2 = fmaf(rdl(hv2.y, c4), w1, a2);
            a2 = fmaf(rdl(hv2.z, c4), w2, a2); a2 = fmaf(rdl(hv2.w, c4), w3, a2);
            a3 = fmaf(rdl(hv3.x, c4), w0, a3); a3 = fmaf(rdl(hv3.y, c4), w1, a3);
            a3 = fmaf(rdl(hv3.z, c4), w2, a3); a3 = fmaf(rdl(hv3.w, c4), w3, a3);
            w0 = p0; w1 = p1; w2 = p2; w3 = p3;
        }
        if (col < C) { vmsh[0][col] = a0; vmsh[1][col] = a1; vmsh[2][col] = a2; vmsh[3][col] = a3; }
    }
    __syncthreads();
    // Phase C: wave-local attention, position = wv
    float att = 0.f;
    {
        int l = (ln >> 2) & 3, m = ln & 3;
        float sc = 0.f;
        if (ln < 16) {
            const float* qv = &lsh[wv][l * HD];
            const float* kv = &rsh[wv][m * HD];
            for (int d = 0; d < HD; ++d) sc = fmaf(qv[d], kv[d], sc);
            sc *= 0.13245323570650439f;  // 1/sqrt(57)
        }
        float mx = fmaxf(sc, __shfl_xor(sc, 1, 4));
        mx = fmaxf(mx, __shfl_xor(mx, 2, 4));
        float e = expf(sc - mx);
        float se = e + __shfl_xor(e, 1, 4);
        se += __shfl_xor(se, 2, 4);
        att = e / se;
    }
    float zreg[4]; int lidx[4];
#pragma unroll
    for (int j = 0; j < 4; ++j) {
        int c = ln + 64 * j;
        zreg[j] = 0.f; lidx[j] = 0;
        if (c < C) {
            int l = (c >= 171) + (c >= 114) + (c >= 57);
            int d = c - 57 * l;
            float b0 = __shfl(att, 4 * l + 0, 64);
            float b1 = __shfl(att, 4 * l + 1, 64);
            float b2 = __shfl(att, 4 * l + 2, 64);
            float b3 = __shfl(att, 4 * l + 3, 64);
            float z = b0 * vmsh[wv][d] + b1 * vmsh[wv][HD + d]
                    + b2 * vmsh[wv][2 * HD + d] + b3 * vmsh[wv][3 * HD + d];
            zsh[wv][c] = z; zreg[j] = z; lidx[j] = l;
        }
    }
    float rs = 0.f;
    if (ln < 4) {
        float zz = 0.f;
        const float* zr = &zsh[wv][ln * HD];
        for (int d = 0; d < HD; ++d) zz = fmaf(zr[d], zr[d], zz);
        rs = rsqrtf(zz * (1.f / HD) + 1e-6f) / (float)(1 + ln);
    }
#pragma unroll
    for (int j = 0; j < 4; ++j) {
        int c = ln + 64 * j;
        if (c < C) {
            float rsl = __shfl(rs, lidx[j], 64);
            dst[(size_t)(nb + wv) * C + c] = lsh[wv][c] + zreg[j] * rsl;
        }
    }
}

// ---------------- fused MLP: x += cproj; LN2; fc+gelu; proj(+res); [LN1'; uv'] ----------------
__global__ __launch_bounds__(256) void mlp_k(const float* __restrict__ q, const float* __restrict__ v,
                                             const float* __restrict__ wcT, const float* __restrict__ g2,
                                             const float* __restrict__ wfcT, const float* __restrict__ wpT,
                                             float* __restrict__ x,
                                             const float* __restrict__ g1n, const float* __restrict__ wuvTn,
                                             float* __restrict__ qout, float* __restrict__ vout) {
    __shared__ __align__(16) float psh[4][256];   // q*v, later x_final
    __shared__ __align__(16) float xm[4][232];    // x + cproj
    __shared__ __align__(16) float hsh[4][256];   // LN outputs
    __shared__ __align__(16) float hid[4][944];   // gelu(fc)
    int tid = threadIdx.x, nb = blockIdx.x * 4;
    int wv = tid >> 6, ln = tid & 63;
    for (int i = tid; i < 4 * 256; i += 256) {
        int p = i >> 8, c = i & 255;
        psh[p][c] = (c < C) ? q[(size_t)(nb + p) * C + c] * v[(size_t)(nb + p) * C + c] : 0.f;
    }
    if (tid < 128) { int p = tid >> 5; hid[p][912 + (tid & 31)] = 0.f; }
    __syncthreads();
    // GEMV1: cproj, xm = x + p @ wcT
    {
        int col = tid, colc = (col < C) ? col : 0;
        f32x4 hv0 = *(const f32x4*)&psh[0][4 * ln];
        f32x4 hv1 = *(const f32x4*)&psh[1][4 * ln];
        f32x4 hv2 = *(const f32x4*)&psh[2][4 * ln];
        f32x4 hv3 = *(const f32x4*)&psh[3][4 * ln];
        float a0 = 0.f, a1 = 0.f, a2 = 0.f, a3 = 0.f;
        const float* wcol = wcT + colc;
        for (int c4 = 0; c4 < 57; ++c4) {
            float w0 = wcol[(size_t)(c4*4+0)*C];
            float w1 = wcol[(size_t)(c4*4+1)*C];
            float w2 = wcol[(size_t)(c4*4+2)*C];
            float w3 = wcol[(size_t)(c4*4+3)*C];
            a0 = fmaf(rdl(hv0.x, c4), w0, a0); a0 = fmaf(rdl(hv0.y, c4), w1, a0);
            a0 = fmaf(rdl(hv0.z, c4), w2, a0); a0 = fmaf(rdl(hv0.w, c4), w3, a0);
            a1 = fmaf(rdl(hv1.x, c4), w0, a1); a1 = fmaf(rdl(hv1.y, c4), w1, a1);
            a1 = fmaf(rdl(hv1.z, c4), w2, a1); a1 = fmaf(rdl(hv1.w, c4), w3, a1);
            a2 = fmaf(rdl(hv2.x, c4), w0, a2); a2 = fmaf(rdl(hv2.y, c4), w1, a2);
            a2 = fmaf(rdl(hv2.z, c4), w2, a2); a2 = fmaf(rdl(hv2.w, c4), w3, a2);
            a3 = fmaf(rdl(hv3.x, c4), w0, a3); a3 = fmaf(rdl(hv3.y, c4), w1, a3);
            a3 = fmaf(rdl(hv3.z, c4), w2, a3); a3 = fmaf(rdl(hv3.w, c4), w3, a3);
        }
        if (col < C) {
            xm[0][col] = x[(size_t)(nb+0)*C + col] + a0;
            xm[1][col] = x[(size_t)(nb+1)*C + col] + a1;
            xm[2][col] = x[(size_t)(nb+2)*C + col] + a2;
            xm[3][col] = x[(size_t)(nb+3)*C + col] + a3;
        }
    }
    __syncthreads();
    // LN2 per wave
    {
        float vals[4]; float s = 0.f, ss = 0.f;
#pragma unroll
        for (int j = 0; j < 4; ++j) {
            int c = ln + 64 * j;
            float vv = (c < C) ? xm[wv][c] : 0.f;
            vals[j] = vv; s += vv; ss += vv * vv;
        }
#pragma unroll
        for (int o = 32; o > 0; o >>= 1) { s += __shfl_xor(s, o, 64); ss += __shfl_xor(ss, o, 64); }
        float mean = s * (1.f / C);
        float rstd = rsqrtf(ss * (1.f / C) - mean * mean + 1e-5f);
#pragma unroll
        for (int j = 0; j < 4; ++j) {
            int c = ln + 64 * j;
            hsh[wv][c] = (c < C) ? (vals[j] - mean) * rstd * g2[c] : 0.f;
        }
    }
    __syncthreads();
    // GEMV2: fc + gelu, 4 cols/thread
    {
        f32x4 hv[4];
#pragma unroll
        for (int p = 0; p < 4; ++p) hv[p] = *(const f32x4*)&hsh[p][4 * ln];
        int c0 = tid, c1 = tid + 256, c2 = tid + 512, c3 = tid + 768;
        int c3v = (c3 < HID);
        const float* wp0 = wfcT + c0;
        const float* wp1 = wfcT + c1;
        const float* wp2 = wfcT + c2;
        const float* wp3 = wfcT + (c3v ? c3 : 0);
        float acc[4][4] = {};
        for (int c4 = 0; c4 < 57; ++c4) {
            float wa0 = wp0[(size_t)(c4*4+0)*HID], wa1 = wp0[(size_t)(c4*4+1)*HID];
            float wa2 = wp0[(size_t)(c4*4+2)*HID], wa3 = wp0[(size_t)(c4*4+3)*HID];
            float wb0 = wp1[(size_t)(c4*4+0)*HID], wb1 = wp1[(size_t)(c4*4+1)*HID];
            float wb2 = wp1[(size_t)(c4*4+2)*HID], wb3 = wp1[(size_t)(c4*4+3)*HID];
            float wc0 = wp2[(size_t)(c4*4+0)*HID], wc1 = wp2[(size_t)(c4*4+1)*HID];
            float wc2 = wp2[(size_t)(c4*4+2)*HID], wc3 = wp2[(size_t)(c4*4+3)*HID];
            float wd0 = wp3[(size_t)(c4*4+0)*HID], wd1 = wp3[(size_t)(c4*4+1)*HID];
            float wd2 = wp3[(size_t)(c4*4+2)*HID], wd3 = wp3[(size_t)(c4*4+3)*HID];
#pragma unroll
            for (int p = 0; p < 4; ++p) {
                float h0 = rdl(hv[p].x, c4), h1 = rdl(hv[p].y, c4);
                float h2 = rdl(hv[p].z, c4), h3 = rdl(hv[p].w, c4);
                acc[0][p] = fmaf(h0, wa0, acc[0][p]); acc[0][p] = fmaf(h1, wa1, acc[0][p]);
                acc[0][p] = fmaf(h2, wa2, acc[0][p]); acc[0][p] = fmaf(h3, wa3, acc[0][p]);
                acc[1][p] = fmaf(h0, wb0, acc[1][p]); acc[1][p] = fmaf(h1, wb1, acc[1][p]);
                acc[1][p] = fmaf(h2, wb2, acc[1][p]); acc[1][p] = fmaf(h3, wb3, acc[1][p]);
                acc[2][p] = fmaf(h0, wc0, acc[2][p]); acc[2][p] = fmaf(h1, wc1, acc[2][p]);
                acc[2][p] = fmaf(h2, wc2, acc[2][p]); acc[2][p] = fmaf(h3, wc3, acc[2][p]);
                acc[3][p] = fmaf(h0, wd0, acc[3][p]); acc[3][p] = fmaf(h1, wd1, acc[3][p]);
                acc[3][p] = fmaf(h2, wd2, acc[3][p]); acc[3][p] = fmaf(h3, wd3, acc[3][p]);
            }
        }
#pragma unroll
        for (int p = 0; p < 4; ++p) {
            float u0 = acc[0][p], u1 = acc[1][p], u2 = acc[2][p], u3 = acc[3][p];
            hid[p][c0] = 0.5f * u0 * (1.f + tanhf(0.7978845608028654f * (u0 + 0.044715f * u0 * u0 * u0)));
            hid[p][c1] = 0.5f * u1 * (1.f + tanhf(0.7978845608028654f * (u1 + 0.044715f * u1 * u1 * u1)));
            hid[p][c2] = 0.5f * u2 * (1.f + tanhf(0.7978845608028654f * (u2 + 0.044715f * u2 * u2 * u2)));
            if (c3v) hid[p][c3] = 0.5f * u3 * (1.f + tanhf(0.7978845608028654f * (u3 + 0.044715f * u3 * u3 * u3)));
        }
    }
    __syncthreads();
    // GEMV3: proj + residual; write x global + psh (x_final)
    {
        int col = tid, colc = (col < C) ? col : 0;
        float a[4] = {0,0,0,0};
        const float* wcol = wpT + colc;
        for (int ch = 0; ch < 4; ++ch) {
            f32x4 hv[4];
#pragma unroll
            for (int p = 0; p < 4; ++p) hv[p] = *(const f32x4*)&hid[p][228 * ch + 4 * ln];
            const float* wch = wcol + (size_t)(228 * ch) * C;
            for (int c4 = 0; c4 < 57; ++c4) {
                float w0 = wch[(size_t)(c4*4+0)*C];
                float w1 = wch[(size_t)(c4*4+1)*C];
                float w2 = wch[(size_t)(c4*4+2)*C];
                float w3 = wch[(size_t)(c4*4+3)*C];
#pragma unroll
                for (int p = 0; p < 4; ++p) {
                    a[p] = fmaf(rdl(hv[p].x, c4), w0, a[p]);
                    a[p] = fmaf(rdl(hv[p].y, c4), w1, a[p]);
                    a[p] = fmaf(rdl(hv[p].z, c4), w2, a[p]);
                    a[p] = fmaf(rdl(hv[p].w, c4), w3, a[p]);
                }
            }
        }
        if (col < C) {
#pragma unroll
            for (int p = 0; p < 4; ++p) {
                float xf = xm[p][col] + a[p];
                x[(size_t)(nb + p) * C + col] = xf;
                psh[p][col] = xf;
            }
        }
    }
    if (qout != nullptr) {
        __syncthreads();
        // LN1 (next layer) per wave from psh
        {
            float vals[4]; float s = 0.f, ss = 0.f;
#pragma unroll
            for (int j = 0; j < 4; ++j) {
                int c = ln + 64 * j;
                float vv = (c < C) ? psh[wv][c] : 0.f;
                vals[j] = vv; s += vv; ss += vv * vv;
            }
#pragma unroll
            for (int o = 32; o > 0; o >>= 1) { s += __shfl_xor(s, o, 64); ss += __shfl_xor(ss, o, 64); }
            float mean = s * (1.f / C);
            float rstd = rsqrtf(ss * (1.f / C) - mean * mean + 1e-5f);
#pragma unroll
            for (int j = 0; j < 4; ++j) {
                int c = ln + 64 * j;
                hsh[wv][c] = (c < C) ? (vals[j] - mean) * rstd * g1n[c] : 0.f;
            }
        }
        __syncthreads();
        // GEMV4: next-layer up/v
        f32x4 hv[4];
#pragma unroll
        for (int p = 0; p < 4; ++p) hv[p] = *(const f32x4*)&hsh[p][4 * ln];
        int col0 = tid, col1 = tid + 256;
        int c1v = (col1 < 2 * C);
        float acc0[4] = {0,0,0,0}, acc1[4] = {0,0,0,0};
        const float* w0p = wuvTn + col0;
        const float* w1p = wuvTn + (c1v ? col1 : 0);
        for (int c4 = 0; c4 < 57; ++c4) {
            float wa0 = w0p[(size_t)(c4*4+0)*(2*C)], wa1 = w0p[(size_t)(c4*4+1)*(2*C)];
            float wa2 = w0p[(size_t)(c4*4+2)*(2*C)], wa3 = w0p[(size_t)(c4*4+3)*(2*C)];
            float wb0 = w1p[(size_t)(c4*4+0)*(2*C)], wb1 = w1p[(size_t)(c4*4+1)*(2*C)];
            float wb2 = w1p[(size_t)(c4*4+2)*(2*C)], wb3 = w1p[(size_t)(c4*4+3)*(2*C)];
#pragma unroll
            for (int p = 0; p < 4; ++p) {
                float h0 = rdl(hv[p].x, c4), h1 = rdl(hv[p].y, c4);
                float h2 = rdl(hv[p].z, c4), h3 = rdl(hv[p].w, c4);
                acc0[p] = fmaf(h0, wa0, acc0[p]); acc0[p] = fmaf(h1, wa1, acc0[p]);
                acc0[p] = fmaf(h2, wa2, acc0[p]); acc0[p] = fmaf(h3, wa3, acc0[p]);
                acc1[p] = fmaf(h0, wb0, acc1[p]); acc1[p] = fmaf(h1, wb1, acc1[p]);
                acc1[p] = fmaf(h2, wb2, acc1[p]); acc1[p] = fmaf(h3, wb3, acc1[p]);
            }
        }
#pragma unroll
        for (int p = 0; p < 4; ++p) {
            if (col0 < C) qout[(size_t)(nb+p)*C + col0] = acc0[p];
            else          vout[(size_t)(nb+p)*C + col0 - C] = acc0[p];
            if (c1v)      vout[(size_t)(nb+p)*C + col1 - C] = acc1[p];
        }
    }
}

// ---------------- bf16 conversions (K padded to 256 with zeros) ----------------
__global__ void convx_k(const float* __restrict__ x, __hip_bfloat16* __restrict__ xbf) {
    int i = blockIdx.x * 256 + threadIdx.x;    // NPOS*KPAD total
    int n = i >> 8, c = i & 255;
    xbf[i] = __float2bfloat16((c < C) ? x[(size_t)n * C + c] : 0.f);
}
__global__ void convw_k(const float* __restrict__ wte, __hip_bfloat16* __restrict__ wbf) {
    size_t i = (size_t)blockIdx.x * 256 + threadIdx.x;   // VOC*KPAD total
    size_t n = i >> 8; int c = (int)(i & 255);
    wbf[i] = __float2bfloat16((c < C) ? wte[n * C + c] : 0.f);
}

// ---------------- lm_head: out[2048][VOC] = A @ B^T (bf16 MFMA) ----------------
__global__ __launch_bounds__(256) void lmhead_k(const __bf16* __restrict__ A,
                                                const __bf16* __restrict__ Bw,
                                                float* __restrict__ out) {
    int lane = threadIdx.x & 63;
    int wave = threadIdx.x >> 6;
    int wm = wave >> 1, wn = wave & 1;
    int m0 = blockIdx.x * 128 + wm * 64;
    int n0 = blockIdx.y * 128 + wn * 64;
    int r  = lane & 15, q = lane >> 4;
    f32x4 acc[4][4] = {};
    const __bf16* Ap = A + (size_t)(m0 + r) * KPAD + q * 8;
    int brow[4];
#pragma unroll
    for (int nt = 0; nt < 4; ++nt) { int rw = n0 + nt * 16 + r; brow[nt] = (rw < VOC) ? rw : 0; }
    for (int kc = 0; kc < 8; ++kc) {
        int ko = kc * 32;
        bf16x8 a[4], b[4];
#pragma unroll
        for (int mt = 0; mt < 4; ++mt)
            a[mt] = *(const bf16x8*)(Ap + (size_t)mt * 16 * KPAD + ko);
#pragma unroll
        for (int nt = 0; nt < 4; ++nt)
            b[nt] = *(const bf16x8*)(Bw + (size_t)brow[nt] * KPAD + q * 8 + ko);
#pragma unroll
        for (int mt = 0; mt < 4; ++mt)
#pragma unroll
            for (int nt = 0; nt < 4; ++nt)
                acc[mt][nt] = __builtin_amdgcn_mfma_f32_16x16x32_bf16(a[mt], b[nt], acc[mt][nt], 0, 0, 0);
    }
#pragma unroll
    for (int mt = 0; mt < 4; ++mt)
#pragma unroll
        for (int nt = 0; nt < 4; ++nt) {
            int col = n0 + nt * 16 + r;
            if (col < VOC) {
#pragma unroll
                for (int rr = 0; rr < 4; ++rr) {
                    int row = m0 + mt * 16 + q * 4 + rr;
                    out[(size_t)row * VOC + col] = acc[mt][nt][rr];
                }
            }
        }
}

extern "C" void kernel_launch(void* const* d_in, const int* in_sizes, int n_in,
                              void* d_out, int out_size, void* d_ws, size_t ws_size,
                              hipStream_t stream) {
    const int*   idx     = (const int*)d_in[0];
    const float* wte     = (const float*)d_in[1];
    const float* ln1_g   = (const float*)d_in[2];
    const float* ln2_g   = (const float*)d_in[3];
    const float* w_up    = (const float*)d_in[4];
    const float* w_v     = (const float*)d_in[5];
    const float* w_cproj = (const float*)d_in[6];
    const float* w_scan  = (const float*)d_in[7];
    const float* identp  = (const float*)d_in[8];
    const float* w_fc    = (const float*)d_in[9];
    const float* w_proj  = (const float*)d_in[10];
    float* out = (float*)d_out;

    float* ws   = (float*)d_ws;
    float* x    = ws;
    float* buf0 = x    + (size_t)NPOS * C;
    float* buf1 = buf0 + (size_t)NPOS * C;
    float* vbuf = buf1 + (size_t)NPOS * C;
    float* wuvT = vbuf + (size_t)NPOS * C;
    float* wcT  = wuvT + (size_t)NLAYER * C * 2 * C;
    float* wfcT = wcT  + (size_t)NLAYER * C * C;
    float* wpT  = wfcT + (size_t)NLAYER * C * HID;
    __hip_bfloat16* xbf   = (__hip_bfloat16*)(wpT + (size_t)NLAYER * HID * C);
    __hip_bfloat16* wtebf = xbf + (size_t)NPOS * KPAD;

    dim3 tg1((C * C + 255) / 256, NLAYER);
    transpose_k<<<tg1, 256, 0, stream>>>(w_up,    wuvT, C, C, 2 * C, 0, C * C, C * 2 * C);
    transpose_k<<<tg1, 256, 0, stream>>>(w_v,     wuvT, C, C, 2 * C, C, C * C, C * 2 * C);
    transpose_k<<<tg1, 256, 0, stream>>>(w_cproj, wcT,  C, C, C,     0, C * C, C * C);
    dim3 tg2((HID * C + 255) / 256, NLAYER);
    transpose_k<<<tg2, 256, 0, stream>>>(w_fc,   wfcT, HID, C, HID, 0, HID * C, C * HID);
    transpose_k<<<tg2, 256, 0, stream>>>(w_proj, wpT,  C, HID, C,   0, C * HID, HID * C);

    embed_k<<<NPOS * C / 256, 256, 0, stream>>>(idx, wte, x);

    lnuv_k<<<NPOS / 4, 256, 0, stream>>>(x, ln1_g, wuvT, buf0, vbuf);
    for (int L = 0; L < NLAYER; ++L) {
        const float* wscan_l = w_scan + (size_t)L * C * C;
        const float* ident_l = identp + (size_t)L * C;
        float* cur = buf0; float* oth = buf1;
        for (int off = 1; off < TT; off <<= 1) {
            scanstep_k<<<NPOS / 4, 256, 0, stream>>>(cur, oth, wscan_l, ident_l, off);
            float* t = cur; cur = oth; oth = t;
        }
        // 10 steps (even) -> result back in buf0
        bool last = (L == NLAYER - 1);
        mlp_k<<<NPOS / 4, 256, 0, stream>>>(buf0, vbuf,
                                            wcT  + (size_t)L * C * C,
                                            ln2_g + L * C,
                                            wfcT + (size_t)L * C * HID,
                                            wpT  + (size_t)L * HID * C,
                                            x,
                                            last ? nullptr : (ln1_g + (size_t)(L + 1) * C),
                                            last ? nullptr : (wuvT + (size_t)(L + 1) * C * 2 * C),
                                            last ? nullptr : buf0,
                                            last ? nullptr : vbuf);
    }

    convx_k<<<NPOS * KPAD / 256, 256, 0, stream>>>(x, xbf);
    convw_k<<<VOC, 256, 0, stream>>>(wte, wtebf);
    lmhead_k<<<dim3(16, 393), 256, 0, stream>>>((const __bf16*)xbf, (const __bf16*)wtebf, out);
}